// Round 3
// baseline (1160.911 us; speedup 1.0000x reference)
//
#include <hip/hip_runtime.h>

#define IN_CH  128
#define HID_CH 64
#define OUT_CH 8

// ---------- edge dtype detector: int64 (raw) vs int32 (converted) ----------
__global__ void detect_k(const int* __restrict__ ei, int* __restrict__ flag) {
    int i = threadIdx.x;
    int seen = 0;
    for (int j = 0; j < 16; ++j) seen |= ei[2 * (i * 16 + j) + 1];
    if (seen) atomicOr(flag, 1);   // nonzero odd word => int32 layout
}

__device__ __forceinline__ int load_src(const int* __restrict__ ei, int is64, int E, int e) {
    return is64 ? ei[2ll * e] : ei[e];
}
__device__ __forceinline__ int load_dst(const int* __restrict__ ei, int is64, int E, int e) {
    return is64 ? ei[2ll * (E + e)] : ei[E + e];
}

// ---------- degree ----------
__global__ void count_deg_k(const int* __restrict__ ei, const int* __restrict__ meta,
                            float* __restrict__ deg, int E) {
    int e = blockIdx.x * blockDim.x + threadIdx.x;
    if (e >= E) return;
    int is64 = (meta[0] == 0);
    atomicAdd(&deg[load_dst(ei, is64, E, e)], 1.0f);
}

__global__ void make_dinv_k(float* __restrict__ deg, int n) {
    int v = blockIdx.x * blockDim.x + threadIdx.x;
    if (v < n) deg[v] = rsqrtf(deg[v] + 1.0f);   // +1 self-loop; always > 0
}

// ---------- h1 = x @ W1   [n,128]x[128,64] ----------
__global__ __launch_bounds__(256) void gemm1_k(const float* __restrict__ x,
                                               const float* __restrict__ W,
                                               float* __restrict__ h, int n) {
    __shared__ float Ws[IN_CH * HID_CH];     // 32 KB
    __shared__ float xs[4][IN_CH];           // 2 KB
    int tid = threadIdx.x;
    for (int i = tid; i < IN_CH * HID_CH; i += 256) Ws[i] = W[i];
    int node0 = blockIdx.x * 4;
    for (int i = tid; i < 4 * IN_CH; i += 256) {
        int nn = i >> 7, k = i & 127;
        int node = node0 + nn;
        xs[nn][k] = (node < n) ? x[node * IN_CH + k] : 0.0f;
    }
    __syncthreads();
    int nl = tid >> 6, oc = tid & 63;
    float acc = 0.0f;
#pragma unroll 8
    for (int k = 0; k < IN_CH; ++k) acc += xs[nl][k] * Ws[k * HID_CH + oc];
    int node = node0 + nl;
    if (node < n) h[node * HID_CH + oc] = acc;
}

// ---------- layer-1 edge scatter: 64 lanes per edge ----------
__global__ __launch_bounds__(256) void agg1_k(const int* __restrict__ ei,
                                              const int* __restrict__ meta,
                                              const float* __restrict__ dinv,
                                              const float* __restrict__ h,
                                              float* __restrict__ agg, int E) {
    long long t = (long long)blockIdx.x * 256 + threadIdx.x;
    int e = (int)(t >> 6), c = (int)(t & 63);
    if (e >= E) return;
    int is64 = (meta[0] == 0);
    int s = load_src(ei, is64, E, e), d = load_dst(ei, is64, E, e);
    float norm = dinv[s] * dinv[d];
    atomicAdd(&agg[(long long)d * HID_CH + c], norm * h[(long long)s * HID_CH + c]);
}

// ---------- self-loop + bias + relu  (z1 written over agg1) ----------
__global__ void post1_k(float* __restrict__ agg, const float* __restrict__ h,
                        const float* __restrict__ dinv, const float* __restrict__ b, int n) {
    int t = blockIdx.x * blockDim.x + threadIdx.x;
    if (t >= n * HID_CH) return;
    int v = t >> 6, c = t & 63;
    float di = dinv[v];
    float val = agg[t] + di * di * h[t] + b[c];
    agg[t] = fmaxf(val, 0.0f);
}

// ---------- h2 = z1 @ W2   [n,64]x[64,8] ----------
__global__ __launch_bounds__(256) void gemm2_k(const float* __restrict__ z,
                                               const float* __restrict__ W,
                                               float* __restrict__ h2, int n) {
    __shared__ float Ws[HID_CH * OUT_CH];    // 512 floats
    int tid = threadIdx.x;
    // BUGFIX (R3): 512 elements, 256 threads -> strided loop, not a single if.
    for (int i = tid; i < HID_CH * OUT_CH; i += 256) Ws[i] = W[i];
    __syncthreads();
    int t = blockIdx.x * 256 + tid;
    int node = t >> 3, oc = t & 7;
    if (node >= n) return;
    float acc = 0.0f;
#pragma unroll
    for (int k = 0; k < HID_CH; ++k) acc += z[node * HID_CH + k] * Ws[k * OUT_CH + oc];
    h2[node * OUT_CH + oc] = acc;
}

// ---------- layer-2 edge scatter: 8 lanes per edge ----------
__global__ __launch_bounds__(256) void agg2_k(const int* __restrict__ ei,
                                              const int* __restrict__ meta,
                                              const float* __restrict__ dinv,
                                              const float* __restrict__ h,
                                              float* __restrict__ agg, int E) {
    long long t = (long long)blockIdx.x * 256 + threadIdx.x;
    int e = (int)(t >> 3), c = (int)(t & 7);
    if (e >= E) return;
    int is64 = (meta[0] == 0);
    int s = load_src(ei, is64, E, e), d = load_dst(ei, is64, E, e);
    float norm = dinv[s] * dinv[d];
    atomicAdd(&agg[(long long)d * OUT_CH + c], norm * h[(long long)s * OUT_CH + c]);
}

// ---------- self-loop + bias + log_softmax ----------
__global__ void final_k(const float* __restrict__ agg2, const float* __restrict__ h2,
                        const float* __restrict__ dinv, const float* __restrict__ b,
                        float* __restrict__ out, int n) {
    int v = blockIdx.x * blockDim.x + threadIdx.x;
    if (v >= n) return;
    float di = dinv[v], di2 = di * di;
    float vals[OUT_CH];
    float m = -1e30f;
#pragma unroll
    for (int c = 0; c < OUT_CH; ++c) {
        vals[c] = agg2[v * OUT_CH + c] + di2 * h2[v * OUT_CH + c] + b[c];
        m = fmaxf(m, vals[c]);
    }
    float sum = 0.0f;
#pragma unroll
    for (int c = 0; c < OUT_CH; ++c) sum += expf(vals[c] - m);
    float lse = m + logf(sum);
#pragma unroll
    for (int c = 0; c < OUT_CH; ++c) out[v * OUT_CH + c] = vals[c] - lse;
}

extern "C" void kernel_launch(void* const* d_in, const int* in_sizes, int n_in,
                              void* d_out, int out_size, void* d_ws, size_t ws_size,
                              hipStream_t stream) {
    const float* x  = (const float*)d_in[0];
    const int*   ei = (const int*)d_in[1];
    const float* W1 = (const float*)d_in[2];
    const float* b1 = (const float*)d_in[3];
    const float* W2 = (const float*)d_in[4];
    const float* b2 = (const float*)d_in[5];
    float* out = (float*)d_out;

    const int n = in_sizes[0] / IN_CH;      // 100000
    const int E = in_sizes[1] / 2;          // 3200000 logical edges

    // workspace layout (floats), with h1-region reuse: 51.6 MB total
    float* ws   = (float*)d_ws;
    int*   meta = (int*)d_ws;                // [1] flag (64-float slot)
    float* dinv = ws + 64;                   // [n] (padded to 100352)
    float* h1   = dinv + 100352;             // [n*64]
    float* agg1 = h1 + 6400000;              // [n*64], becomes z1
    float* h2   = h1;                        // reuse: [n*8], h1 dead after post1
    float* agg2 = h1 + 800000;               // reuse: [n*8]

    hipMemsetAsync(meta, 0, sizeof(int), stream);
    hipMemsetAsync(dinv, 0, (size_t)n * sizeof(float), stream);
    hipMemsetAsync(agg1, 0, (size_t)n * HID_CH * sizeof(float), stream);

    detect_k<<<1, 256, 0, stream>>>(ei, meta);
    count_deg_k<<<(E + 255) / 256, 256, 0, stream>>>(ei, meta, dinv, E);
    make_dinv_k<<<(n + 255) / 256, 256, 0, stream>>>(dinv, n);
    gemm1_k<<<(n + 3) / 4, 256, 0, stream>>>(x, W1, h1, n);
    agg1_k<<<(int)(((long long)E * 64 + 255) / 256), 256, 0, stream>>>(ei, meta, dinv, h1, agg1, E);
    post1_k<<<(n * HID_CH + 255) / 256, 256, 0, stream>>>(agg1, h1, dinv, b1, n);
    hipMemsetAsync(agg2, 0, (size_t)n * OUT_CH * sizeof(float), stream);
    gemm2_k<<<(n * OUT_CH + 255) / 256, 256, 0, stream>>>(agg1, W2, h2, n);
    agg2_k<<<(int)(((long long)E * 8 + 255) / 256), 256, 0, stream>>>(ei, meta, dinv, h2, agg2, E);
    final_k<<<(n + 255) / 256, 256, 0, stream>>>(agg2, h2, dinv, b2, out, n);
}

// Round 4
// 802.812 us; speedup vs baseline: 1.4461x; 1.4461x over previous
//
#include <hip/hip_runtime.h>

#define IN_CH  128
#define HID_CH 64
#define OUT_CH 8

// edge_index arrives as int32 (confirmed R1 vs R2: identical absmax with/without
// int64 detection => int32 layout). src = ei[0..E), dst = ei[E..2E).

// ---------- 1. histogram of dst degrees (int) ----------
__global__ void hist_k(const int* __restrict__ dst, int* __restrict__ deg, int E) {
    int e = blockIdx.x * blockDim.x + threadIdx.x;
    if (e < E) atomicAdd(&deg[dst[e]], 1);
}

// ---------- 2a. per-block inclusive scan of deg ----------
__global__ __launch_bounds__(256) void scanA_k(const int* __restrict__ deg,
                                               int* __restrict__ incl,
                                               int* __restrict__ parts, int n) {
    __shared__ int sd[256];
    int t = threadIdx.x, v = blockIdx.x * 256 + t;
    int x = (v < n) ? deg[v] : 0;
    sd[t] = x; __syncthreads();
    for (int o = 1; o < 256; o <<= 1) {
        int y = (t >= o) ? sd[t - o] : 0;
        __syncthreads();
        sd[t] += y; __syncthreads();
    }
    if (v < n) incl[v] = sd[t];
    if (t == 255) parts[blockIdx.x] = sd[255];
}

// ---------- 2b. single-block exclusive scan of block totals ----------
__global__ __launch_bounds__(512) void scanB_k(int* __restrict__ parts, int nb) {
    __shared__ int sd[512];
    int t = threadIdx.x;
    int x = (t < nb) ? parts[t] : 0;
    sd[t] = x; __syncthreads();
    for (int o = 1; o < 512; o <<= 1) {
        int y = (t >= o) ? sd[t - o] : 0;
        __syncthreads();
        sd[t] += y; __syncthreads();
    }
    parts[t] = sd[t] - x;   // exclusive
}

// ---------- 2c. finalize: off (excl start), cursor, dinv ----------
__global__ void scanC_k(const int* __restrict__ deg, const int* __restrict__ incl,
                        const int* __restrict__ parts, int* __restrict__ off,
                        int* __restrict__ cur, float* __restrict__ dinv, int n) {
    int v = blockIdx.x * blockDim.x + threadIdx.x;
    if (v >= n) return;
    int d = deg[v];
    int o = parts[blockIdx.x] + incl[v] - d;
    off[v] = o;
    cur[v] = o;
    dinv[v] = rsqrtf((float)d + 1.0f);   // +1 self-loop
}

// ---------- 3. fill CSR (src ids bucketed by dst) ----------
__global__ void fill_k(const int* __restrict__ ei, int* __restrict__ cur,
                       int* __restrict__ csr, int E) {
    int e = blockIdx.x * blockDim.x + threadIdx.x;
    if (e >= E) return;
    int s = ei[e], d = ei[E + e];
    int slot = atomicAdd(&cur[d], 1);
    csr[slot] = s;
}

// ---------- 4. h1 = x @ W1   [n,128]x[128,64], 16 nodes/block ----------
__global__ __launch_bounds__(256) void gemm1_k(const float* __restrict__ x,
                                               const float* __restrict__ W,
                                               float* __restrict__ h, int n) {
    __shared__ float Ws[IN_CH * HID_CH];     // 32 KB
    __shared__ float xs[16][IN_CH];          // 8 KB
    int tid = threadIdx.x;
    for (int i = tid; i < IN_CH * HID_CH; i += 256) Ws[i] = W[i];
    int node0 = blockIdx.x * 16;
    for (int i = tid; i < 16 * IN_CH; i += 256) {
        int nn = i >> 7, k = i & 127;
        int node = node0 + nn;
        xs[nn][k] = (node < n) ? x[node * IN_CH + k] : 0.0f;
    }
    __syncthreads();
    int nl = tid >> 6, oc = tid & 63;
    float a0 = 0, a1 = 0, a2 = 0, a3 = 0;
#pragma unroll 8
    for (int k = 0; k < IN_CH; ++k) {
        float w = Ws[k * HID_CH + oc];
        a0 += xs[nl][k] * w;
        a1 += xs[nl + 4][k] * w;
        a2 += xs[nl + 8][k] * w;
        a3 += xs[nl + 12][k] * w;
    }
    int v0 = node0 + nl;
    if (v0      < n) h[(v0     ) * HID_CH + oc] = a0;
    if (v0 + 4  < n) h[(v0 + 4 ) * HID_CH + oc] = a1;
    if (v0 + 8  < n) h[(v0 + 8 ) * HID_CH + oc] = a2;
    if (v0 + 12 < n) h[(v0 + 12) * HID_CH + oc] = a3;
}

// ---------- 5. layer-1 gather + self-loop + bias + relu (fused) ----------
// one 64-lane wave per node; lane = channel
__global__ __launch_bounds__(256) void agg1_gather_k(const int* __restrict__ off,
                                                     const int* __restrict__ deg,
                                                     const int* __restrict__ csr,
                                                     const float* __restrict__ dinv,
                                                     const float* __restrict__ h,
                                                     const float* __restrict__ b,
                                                     float* __restrict__ z, int n) {
    int node = blockIdx.x * 4 + (threadIdx.x >> 6);
    int lane = threadIdx.x & 63;
    if (node >= n) return;
    float dv = dinv[node];
    int o = off[node], dg = deg[node];
    float acc = 0.0f;
    for (int i = o; i < o + dg; ++i) {
        int s = csr[i];
        acc += dinv[s] * h[(long long)s * HID_CH + lane];
    }
    float val = dv * acc + dv * dv * h[(long long)node * HID_CH + lane] + b[lane];
    z[(long long)node * HID_CH + lane] = fmaxf(val, 0.0f);
}

// ---------- 6. h2 = z1 @ W2   [n,64]x[64,8] ----------
__global__ __launch_bounds__(256) void gemm2_k(const float* __restrict__ z,
                                               const float* __restrict__ W,
                                               float* __restrict__ h2, int n) {
    __shared__ float Ws[HID_CH * OUT_CH];    // 512 floats
    int tid = threadIdx.x;
    for (int i = tid; i < HID_CH * OUT_CH; i += 256) Ws[i] = W[i];
    __syncthreads();
    int t = blockIdx.x * 256 + tid;
    int node = t >> 3, oc = t & 7;
    if (node >= n) return;
    float acc = 0.0f;
#pragma unroll
    for (int k = 0; k < HID_CH; ++k) acc += z[node * HID_CH + k] * Ws[k * OUT_CH + oc];
    h2[node * OUT_CH + oc] = acc;
}

// ---------- 7. layer-2 gather + self-loop + bias + log_softmax (fused) ----------
// 8 lanes per node (32 nodes / block); softmax via width-8 shfl_xor
__global__ __launch_bounds__(256) void agg2_final_k(const int* __restrict__ off,
                                                    const int* __restrict__ deg,
                                                    const int* __restrict__ csr,
                                                    const float* __restrict__ dinv,
                                                    const float* __restrict__ h2,
                                                    const float* __restrict__ b,
                                                    float* __restrict__ out, int n) {
    int tid = threadIdx.x;
    int node = blockIdx.x * 32 + (tid >> 3);
    int c = tid & 7;
    if (node >= n) return;
    float dv = dinv[node];
    int o = off[node], dg = deg[node];
    float acc = 0.0f;
    for (int i = o; i < o + dg; ++i) {
        int s = csr[i];
        acc += dinv[s] * h2[s * OUT_CH + c];
    }
    float val = dv * acc + dv * dv * h2[node * OUT_CH + c] + b[c];
    // log-softmax over the 8 lanes of this node
    float m = val;
    m = fmaxf(m, __shfl_xor(m, 1, 8));
    m = fmaxf(m, __shfl_xor(m, 2, 8));
    m = fmaxf(m, __shfl_xor(m, 4, 8));
    float s8 = expf(val - m);
    s8 += __shfl_xor(s8, 1, 8);
    s8 += __shfl_xor(s8, 2, 8);
    s8 += __shfl_xor(s8, 4, 8);
    out[node * OUT_CH + c] = val - m - logf(s8);
}

extern "C" void kernel_launch(void* const* d_in, const int* in_sizes, int n_in,
                              void* d_out, int out_size, void* d_ws, size_t ws_size,
                              hipStream_t stream) {
    const float* x  = (const float*)d_in[0];
    const int*   ei = (const int*)d_in[1];
    const float* W1 = (const float*)d_in[2];
    const float* b1 = (const float*)d_in[3];
    const float* W2 = (const float*)d_in[4];
    const float* b2 = (const float*)d_in[5];
    float* out = (float*)d_out;

    const int n = in_sizes[0] / IN_CH;      // 100000
    const int E = in_sizes[1] / 2;          // 3200000
    const int NP = 100352;                  // n padded

    // ---- workspace layout (≈66 MB) ----
    int*   deg  = (int*)d_ws;               // [NP]
    int*   incl = deg  + NP;                // [NP]
    int*   parts= incl + NP;                // [512]
    int*   off  = parts+ 512;               // [NP]
    int*   cur  = off  + NP;                // [NP]
    float* dinv = (float*)(cur + NP);       // [NP]
    int*   csr  = (int*)(dinv + NP);        // [E]
    float* h1   = (float*)(csr + E);        // [n*64]
    float* z1   = h1 + (size_t)n * HID_CH;  // [n*64]
    float* h2   = h1;                       // overlay: h1 dead after agg1_gather

    const int nb = (n + 255) / 256;         // 391 scan blocks

    hipMemsetAsync(deg, 0, (size_t)n * sizeof(int), stream);
    hist_k <<<(E + 255) / 256, 256, 0, stream>>>(ei + E, deg, E);
    scanA_k<<<nb, 256, 0, stream>>>(deg, incl, parts, n);
    scanB_k<<<1, 512, 0, stream>>>(parts, nb);
    scanC_k<<<nb, 256, 0, stream>>>(deg, incl, parts, off, cur, dinv, n);
    fill_k <<<(E + 255) / 256, 256, 0, stream>>>(ei, cur, csr, E);
    gemm1_k<<<(n + 15) / 16, 256, 0, stream>>>(x, W1, h1, n);
    agg1_gather_k<<<(n + 3) / 4, 256, 0, stream>>>(off, deg, csr, dinv, h1, b1, z1, n);
    gemm2_k<<<(n * OUT_CH + 255) / 256, 256, 0, stream>>>(z1, W2, h2, n);
    agg2_final_k<<<(n + 31) / 32, 256, 0, stream>>>(off, deg, csr, dinv, h2, b2, out, n);
}

// Round 5
// 679.216 us; speedup vs baseline: 1.7092x; 1.1820x over previous
//
#include <hip/hip_runtime.h>

#define IN_CH  128
#define HID_CH 64
#define OUT_CH 8
#define NRANGE 8   // ranges keyed to blockIdx&7 ~ XCD id (T1 lore); csr region/range ~1.6MB -> L2-local

// edge_index arrives as int32. src = ei[0..E), dst = ei[E..2E).

// ---------- 1. histogram of dst degrees (int) ----------
__global__ void hist_k(const int* __restrict__ dst, int* __restrict__ deg, int E) {
    int e = blockIdx.x * blockDim.x + threadIdx.x;
    if (e < E) atomicAdd(&deg[dst[e]], 1);
}

// ---------- 2a. per-block inclusive scan of deg ----------
__global__ __launch_bounds__(256) void scanA_k(const int* __restrict__ deg,
                                               int* __restrict__ incl,
                                               int* __restrict__ parts, int n) {
    __shared__ int sd[256];
    int t = threadIdx.x, v = blockIdx.x * 256 + t;
    int x = (v < n) ? deg[v] : 0;
    sd[t] = x; __syncthreads();
    for (int o = 1; o < 256; o <<= 1) {
        int y = (t >= o) ? sd[t - o] : 0;
        __syncthreads();
        sd[t] += y; __syncthreads();
    }
    if (v < n) incl[v] = sd[t];
    if (t == 255) parts[blockIdx.x] = sd[255];
}

// ---------- 2b. single-block exclusive scan of block totals ----------
__global__ __launch_bounds__(512) void scanB_k(int* __restrict__ parts, int nb) {
    __shared__ int sd[512];
    int t = threadIdx.x;
    int x = (t < nb) ? parts[t] : 0;
    sd[t] = x; __syncthreads();
    for (int o = 1; o < 512; o <<= 1) {
        int y = (t >= o) ? sd[t - o] : 0;
        __syncthreads();
        sd[t] += y; __syncthreads();
    }
    parts[t] = sd[t] - x;   // exclusive
}

// ---------- 2c. finalize: off (excl start), cursor, dinv ----------
__global__ void scanC_k(const int* __restrict__ deg, const int* __restrict__ incl,
                        const int* __restrict__ parts, int* __restrict__ off,
                        int* __restrict__ cur, float* __restrict__ dinv, int n) {
    int v = blockIdx.x * blockDim.x + threadIdx.x;
    if (v >= n) return;
    int d = deg[v];
    int o = parts[blockIdx.x] + incl[v] - d;
    off[v] = o;
    cur[v] = o;
    dinv[v] = rsqrtf((float)d + 1.0f);   // +1 self-loop
}

// ---------- 3. ranged CSR fill: dst-range == blockIdx&7 -> writes stay XCD-L2-local ----------
__global__ __launch_bounds__(256) void fill_ranged_k(const int* __restrict__ ei,
                                                     int* __restrict__ cur,
                                                     int* __restrict__ csr,
                                                     int E, int n, int G) {
    int r = blockIdx.x & (NRANGE - 1);
    int j = blockIdx.x >> 3;                 // slice within range-group
    int RSZ = (n + NRANGE - 1) / NRANGE;
    int lo = r * RSZ;
    int hi = lo + RSZ; if (hi > n) hi = n;
    const int* __restrict__ src = ei;
    const int* __restrict__ dst = ei + E;
    for (long long e0 = (long long)j * 256; e0 < E; e0 += (long long)G * 256) {
        int e = (int)e0 + threadIdx.x;
        if (e < E) {
            int d = dst[e];
            if (d >= lo && d < hi) {
                int s = src[e];
                int slot = atomicAdd(&cur[d], 1);
                csr[slot] = s;
            }
        }
    }
}

// ---------- 4. h1 = x @ W1   [n,128]x[128,64], 16 nodes/block ----------
__global__ __launch_bounds__(256) void gemm1_k(const float* __restrict__ x,
                                               const float* __restrict__ W,
                                               float* __restrict__ h, int n) {
    __shared__ float Ws[IN_CH * HID_CH];     // 32 KB
    __shared__ float xs[16][IN_CH];          // 8 KB
    int tid = threadIdx.x;
    for (int i = tid; i < IN_CH * HID_CH; i += 256) Ws[i] = W[i];
    int node0 = blockIdx.x * 16;
    for (int i = tid; i < 16 * IN_CH; i += 256) {
        int nn = i >> 7, k = i & 127;
        int node = node0 + nn;
        xs[nn][k] = (node < n) ? x[node * IN_CH + k] : 0.0f;
    }
    __syncthreads();
    int nl = tid >> 6, oc = tid & 63;
    float a0 = 0, a1 = 0, a2 = 0, a3 = 0;
#pragma unroll 8
    for (int k = 0; k < IN_CH; ++k) {
        float w = Ws[k * HID_CH + oc];
        a0 += xs[nl][k] * w;
        a1 += xs[nl + 4][k] * w;
        a2 += xs[nl + 8][k] * w;
        a3 += xs[nl + 12][k] * w;
    }
    int v0 = node0 + nl;
    if (v0      < n) h[(v0     ) * HID_CH + oc] = a0;
    if (v0 + 4  < n) h[(v0 + 4 ) * HID_CH + oc] = a1;
    if (v0 + 8  < n) h[(v0 + 8 ) * HID_CH + oc] = a2;
    if (v0 + 12 < n) h[(v0 + 12) * HID_CH + oc] = a3;
}

// ---------- 5. layer-1 gather + self-loop + bias + relu (fused) ----------
__global__ __launch_bounds__(256) void agg1_gather_k(const int* __restrict__ off,
                                                     const int* __restrict__ deg,
                                                     const int* __restrict__ csr,
                                                     const float* __restrict__ dinv,
                                                     const float* __restrict__ h,
                                                     const float* __restrict__ b,
                                                     float* __restrict__ z, int n) {
    int node = blockIdx.x * 4 + (threadIdx.x >> 6);
    int lane = threadIdx.x & 63;
    if (node >= n) return;
    float dv = dinv[node];
    int o = off[node], dg = deg[node];
    float acc = 0.0f;
    for (int i = o; i < o + dg; ++i) {
        int s = csr[i];
        acc += dinv[s] * h[(long long)s * HID_CH + lane];
    }
    float val = dv * acc + dv * dv * h[(long long)node * HID_CH + lane] + b[lane];
    z[(long long)node * HID_CH + lane] = fmaxf(val, 0.0f);
}

// ---------- 6. h2 = z1 @ W2   [n,64]x[64,8] ----------
__global__ __launch_bounds__(256) void gemm2_k(const float* __restrict__ z,
                                               const float* __restrict__ W,
                                               float* __restrict__ h2, int n) {
    __shared__ float Ws[HID_CH * OUT_CH];    // 512 floats
    int tid = threadIdx.x;
    for (int i = tid; i < HID_CH * OUT_CH; i += 256) Ws[i] = W[i];
    __syncthreads();
    int t = blockIdx.x * 256 + tid;
    int node = t >> 3, oc = t & 7;
    if (node >= n) return;
    float acc = 0.0f;
#pragma unroll
    for (int k = 0; k < HID_CH; ++k) acc += z[node * HID_CH + k] * Ws[k * OUT_CH + oc];
    h2[node * OUT_CH + oc] = acc;
}

// ---------- 7. layer-2 gather + self-loop + bias + log_softmax (fused) ----------
__global__ __launch_bounds__(256) void agg2_final_k(const int* __restrict__ off,
                                                    const int* __restrict__ deg,
                                                    const int* __restrict__ csr,
                                                    const float* __restrict__ dinv,
                                                    const float* __restrict__ h2,
                                                    const float* __restrict__ b,
                                                    float* __restrict__ out, int n) {
    int tid = threadIdx.x;
    int node = blockIdx.x * 32 + (tid >> 3);
    int c = tid & 7;
    if (node >= n) return;
    float dv = dinv[node];
    int o = off[node], dg = deg[node];
    float acc = 0.0f;
    for (int i = o; i < o + dg; ++i) {
        int s = csr[i];
        acc += dinv[s] * h2[s * OUT_CH + c];
    }
    float val = dv * acc + dv * dv * h2[node * OUT_CH + c] + b[c];
    float m = val;
    m = fmaxf(m, __shfl_xor(m, 1, 8));
    m = fmaxf(m, __shfl_xor(m, 2, 8));
    m = fmaxf(m, __shfl_xor(m, 4, 8));
    float s8 = expf(val - m);
    s8 += __shfl_xor(s8, 1, 8);
    s8 += __shfl_xor(s8, 2, 8);
    s8 += __shfl_xor(s8, 4, 8);
    out[node * OUT_CH + c] = val - m - logf(s8);
}

extern "C" void kernel_launch(void* const* d_in, const int* in_sizes, int n_in,
                              void* d_out, int out_size, void* d_ws, size_t ws_size,
                              hipStream_t stream) {
    const float* x  = (const float*)d_in[0];
    const int*   ei = (const int*)d_in[1];
    const float* W1 = (const float*)d_in[2];
    const float* b1 = (const float*)d_in[3];
    const float* W2 = (const float*)d_in[4];
    const float* b2 = (const float*)d_in[5];
    float* out = (float*)d_out;

    const int n = in_sizes[0] / IN_CH;      // 100000
    const int E = in_sizes[1] / 2;          // 3200000
    const int NP = 100352;                  // n padded

    // ---- workspace layout (≈66 MB) ----
    int*   deg  = (int*)d_ws;               // [NP]
    int*   incl = deg  + NP;                // [NP]
    int*   parts= incl + NP;                // [512]
    int*   off  = parts+ 512;               // [NP]
    int*   cur  = off  + NP;                // [NP]
    float* dinv = (float*)(cur + NP);       // [NP]
    int*   csr  = (int*)(dinv + NP);        // [E]
    float* h1   = (float*)(csr + E);        // [n*64]
    float* z1   = h1 + (size_t)n * HID_CH;  // [n*64]
    float* h2   = h1;                       // overlay: h1 dead after agg1_gather

    const int nb = (n + 255) / 256;         // 391 scan blocks
    const int G  = 256;                     // slices per range-group (grid = 8*G)

    hipMemsetAsync(deg, 0, (size_t)n * sizeof(int), stream);
    hist_k <<<(E + 255) / 256, 256, 0, stream>>>(ei + E, deg, E);
    scanA_k<<<nb, 256, 0, stream>>>(deg, incl, parts, n);
    scanB_k<<<1, 512, 0, stream>>>(parts, nb);
    scanC_k<<<nb, 256, 0, stream>>>(deg, incl, parts, off, cur, dinv, n);
    fill_ranged_k<<<NRANGE * G, 256, 0, stream>>>(ei, cur, csr, E, n, G);
    gemm1_k<<<(n + 15) / 16, 256, 0, stream>>>(x, W1, h1, n);
    agg1_gather_k<<<(n + 3) / 4, 256, 0, stream>>>(off, deg, csr, dinv, h1, b1, z1, n);
    gemm2_k<<<(n * OUT_CH + 255) / 256, 256, 0, stream>>>(z1, W2, h2, n);
    agg2_final_k<<<(n + 31) / 32, 256, 0, stream>>>(off, deg, csr, dinv, h2, b2, out, n);
}

// Round 6
// 543.117 us; speedup vs baseline: 2.1375x; 1.2506x over previous
//
#include <hip/hip_runtime.h>
#include <hip/hip_fp16.h>

#define IN_CH  128
#define HID_CH 64
#define OUT_CH 8
#define NRANGE 8   // csr write region per range ~1.6MB -> XCD-L2-local

// edge_index arrives as int32. src = ei[0..E), dst = ei[E..2E).

// ---------- 1. histogram of dst degrees (int) ----------
__global__ void hist_k(const int* __restrict__ dst, int* __restrict__ deg, int E) {
    int e = blockIdx.x * blockDim.x + threadIdx.x;
    if (e < E) atomicAdd(&deg[dst[e]], 1);
}

// ---------- 2a. per-block inclusive scan of deg ----------
__global__ __launch_bounds__(256) void scanA_k(const int* __restrict__ deg,
                                               int* __restrict__ incl,
                                               int* __restrict__ parts, int n) {
    __shared__ int sd[256];
    int t = threadIdx.x, v = blockIdx.x * 256 + t;
    int x = (v < n) ? deg[v] : 0;
    sd[t] = x; __syncthreads();
    for (int o = 1; o < 256; o <<= 1) {
        int y = (t >= o) ? sd[t - o] : 0;
        __syncthreads();
        sd[t] += y; __syncthreads();
    }
    if (v < n) incl[v] = sd[t];
    if (t == 255) parts[blockIdx.x] = sd[255];
}

// ---------- 2b. single-block exclusive scan of block totals ----------
__global__ __launch_bounds__(512) void scanB_k(int* __restrict__ parts, int nb) {
    __shared__ int sd[512];
    int t = threadIdx.x;
    int x = (t < nb) ? parts[t] : 0;
    sd[t] = x; __syncthreads();
    for (int o = 1; o < 512; o <<= 1) {
        int y = (t >= o) ? sd[t - o] : 0;
        __syncthreads();
        sd[t] += y; __syncthreads();
    }
    parts[t] = sd[t] - x;   // exclusive
}

// ---------- 2c. finalize: off (excl start), cursor, dinv ----------
__global__ void scanC_k(const int* __restrict__ deg, const int* __restrict__ incl,
                        const int* __restrict__ parts, int* __restrict__ off,
                        int* __restrict__ cur, float* __restrict__ dinv, int n) {
    int v = blockIdx.x * blockDim.x + threadIdx.x;
    if (v >= n) return;
    int d = deg[v];
    int o = parts[blockIdx.x] + incl[v] - d;
    off[v] = o;
    cur[v] = o;
    dinv[v] = rsqrtf((float)d + 1.0f);   // +1 self-loop
}

// ---------- 3. ranged CSR fill (XCD-L2-local writes) ----------
__global__ __launch_bounds__(256) void fill_ranged_k(const int* __restrict__ ei,
                                                     int* __restrict__ cur,
                                                     int* __restrict__ csr,
                                                     int E, int n, int G) {
    int r = blockIdx.x & (NRANGE - 1);
    int j = blockIdx.x >> 3;
    int RSZ = (n + NRANGE - 1) / NRANGE;
    int lo = r * RSZ;
    int hi = lo + RSZ; if (hi > n) hi = n;
    const int* __restrict__ src = ei;
    const int* __restrict__ dst = ei + E;
    for (long long e0 = (long long)j * 256; e0 < E; e0 += (long long)G * 256) {
        int e = (int)e0 + threadIdx.x;
        if (e < E) {
            int d = dst[e];
            if (d >= lo && d < hi) {
                int s = src[e];
                int slot = atomicAdd(&cur[d], 1);
                csr[slot] = s;
            }
        }
    }
}

// ---------- 4. h1 = x @ W1  -> fp16   [n,128]x[128,64], 16 nodes/block ----------
__global__ __launch_bounds__(256) void gemm1_k(const float* __restrict__ x,
                                               const float* __restrict__ W,
                                               __half* __restrict__ h, int n) {
    __shared__ float Ws[IN_CH * HID_CH];     // 32 KB
    __shared__ float xs[16][IN_CH];          // 8 KB
    int tid = threadIdx.x;
    for (int i = tid; i < IN_CH * HID_CH; i += 256) Ws[i] = W[i];
    int node0 = blockIdx.x * 16;
    for (int i = tid; i < 16 * IN_CH; i += 256) {
        int nn = i >> 7, k = i & 127;
        int node = node0 + nn;
        xs[nn][k] = (node < n) ? x[node * IN_CH + k] : 0.0f;
    }
    __syncthreads();
    int nl = tid >> 6, oc = tid & 63;
    float a0 = 0, a1 = 0, a2 = 0, a3 = 0;
#pragma unroll 8
    for (int k = 0; k < IN_CH; ++k) {
        float w = Ws[k * HID_CH + oc];
        a0 += xs[nl][k] * w;
        a1 += xs[nl + 4][k] * w;
        a2 += xs[nl + 8][k] * w;
        a3 += xs[nl + 12][k] * w;
    }
    int v0 = node0 + nl;
    if (v0      < n) h[(size_t)(v0     ) * HID_CH + oc] = __float2half(a0);
    if (v0 + 4  < n) h[(size_t)(v0 + 4 ) * HID_CH + oc] = __float2half(a1);
    if (v0 + 8  < n) h[(size_t)(v0 + 8 ) * HID_CH + oc] = __float2half(a2);
    if (v0 + 12 < n) h[(size_t)(v0 + 12) * HID_CH + oc] = __float2half(a3);
}

// ---------- 5. layer-1 gather (fp16 rows) + self-loop + bias + relu ----------
__global__ __launch_bounds__(256) void agg1_gather_k(const int* __restrict__ off,
                                                     const int* __restrict__ deg,
                                                     const int* __restrict__ csr,
                                                     const float* __restrict__ dinv,
                                                     const __half* __restrict__ h,
                                                     const float* __restrict__ b,
                                                     float* __restrict__ z, int n) {
    int node = blockIdx.x * 4 + (threadIdx.x >> 6);
    int lane = threadIdx.x & 63;
    if (node >= n) return;
    float dv = dinv[node];
    int o = off[node], dg = deg[node];
    float acc0 = 0.0f, acc1 = 0.0f;
    int i = o, end = o + dg;
    for (; i + 1 < end; i += 2) {
        int s0 = csr[i], s1 = csr[i + 1];
        acc0 += dinv[s0] * __half2float(h[(size_t)s0 * HID_CH + lane]);
        acc1 += dinv[s1] * __half2float(h[(size_t)s1 * HID_CH + lane]);
    }
    if (i < end) {
        int s = csr[i];
        acc0 += dinv[s] * __half2float(h[(size_t)s * HID_CH + lane]);
    }
    float self = __half2float(h[(size_t)node * HID_CH + lane]);
    float val = dv * (acc0 + acc1) + dv * dv * self + b[lane];
    z[(size_t)node * HID_CH + lane] = fmaxf(val, 0.0f);
}

// ---------- 6. h2 = z1 @ W2 -> fp16   [n,64]x[64,8] ----------
__global__ __launch_bounds__(256) void gemm2_k(const float* __restrict__ z,
                                               const float* __restrict__ W,
                                               __half* __restrict__ h2, int n) {
    __shared__ float Ws[HID_CH * OUT_CH];    // 512 floats
    int tid = threadIdx.x;
    for (int i = tid; i < HID_CH * OUT_CH; i += 256) Ws[i] = W[i];
    __syncthreads();
    int t = blockIdx.x * 256 + tid;
    int node = t >> 3, oc = t & 7;
    if (node >= n) return;
    float acc = 0.0f;
#pragma unroll
    for (int k = 0; k < HID_CH; ++k) acc += z[(size_t)node * HID_CH + k] * Ws[k * OUT_CH + oc];
    h2[(size_t)node * OUT_CH + oc] = __float2half(acc);
}

// ---------- 7. layer-2 gather (fp16) + self-loop + bias + log_softmax ----------
__global__ __launch_bounds__(256) void agg2_final_k(const int* __restrict__ off,
                                                    const int* __restrict__ deg,
                                                    const int* __restrict__ csr,
                                                    const float* __restrict__ dinv,
                                                    const __half* __restrict__ h2,
                                                    const float* __restrict__ b,
                                                    float* __restrict__ out, int n) {
    int tid = threadIdx.x;
    int node = blockIdx.x * 32 + (tid >> 3);
    int c = tid & 7;
    if (node >= n) return;
    float dv = dinv[node];
    int o = off[node], dg = deg[node];
    float acc0 = 0.0f, acc1 = 0.0f;
    int i = o, end = o + dg;
    for (; i + 1 < end; i += 2) {
        int s0 = csr[i], s1 = csr[i + 1];
        acc0 += dinv[s0] * __half2float(h2[(size_t)s0 * OUT_CH + c]);
        acc1 += dinv[s1] * __half2float(h2[(size_t)s1 * OUT_CH + c]);
    }
    if (i < end) {
        int s = csr[i];
        acc0 += dinv[s] * __half2float(h2[(size_t)s * OUT_CH + c]);
    }
    float self = __half2float(h2[(size_t)node * OUT_CH + c]);
    float val = dv * (acc0 + acc1) + dv * dv * self + b[c];
    float m = val;
    m = fmaxf(m, __shfl_xor(m, 1, 8));
    m = fmaxf(m, __shfl_xor(m, 2, 8));
    m = fmaxf(m, __shfl_xor(m, 4, 8));
    float s8 = expf(val - m);
    s8 += __shfl_xor(s8, 1, 8);
    s8 += __shfl_xor(s8, 2, 8);
    s8 += __shfl_xor(s8, 4, 8);
    out[(size_t)node * OUT_CH + c] = val - m - logf(s8);
}

extern "C" void kernel_launch(void* const* d_in, const int* in_sizes, int n_in,
                              void* d_out, int out_size, void* d_ws, size_t ws_size,
                              hipStream_t stream) {
    const float* x  = (const float*)d_in[0];
    const int*   ei = (const int*)d_in[1];
    const float* W1 = (const float*)d_in[2];
    const float* b1 = (const float*)d_in[3];
    const float* W2 = (const float*)d_in[4];
    const float* b2 = (const float*)d_in[5];
    float* out = (float*)d_out;

    const int n = in_sizes[0] / IN_CH;      // 100000
    const int E = in_sizes[1] / 2;          // 3200000
    const int NP = 100352;                  // n padded

    // ---- workspace layout ----
    int*    deg  = (int*)d_ws;              // [NP]
    int*    incl = deg  + NP;               // [NP]
    int*    parts= incl + NP;               // [512]
    int*    off  = parts+ 512;              // [NP]
    int*    cur  = off  + NP;               // [NP]
    float*  dinv = (float*)(cur + NP);      // [NP]
    int*    csr  = (int*)(dinv + NP);       // [E]
    __half* h1   = (__half*)(csr + E);      // [n*64] fp16 (12.8 MB)
    float*  z1   = (float*)(h1 + (size_t)NP * HID_CH);  // [n*64] fp32
    __half* h2   = h1;                      // overlay: h1 dead after agg1_gather

    const int nb = (n + 255) / 256;
    const int G  = 256;

    hipMemsetAsync(deg, 0, (size_t)n * sizeof(int), stream);
    hist_k <<<(E + 255) / 256, 256, 0, stream>>>(ei + E, deg, E);
    scanA_k<<<nb, 256, 0, stream>>>(deg, incl, parts, n);
    scanB_k<<<1, 512, 0, stream>>>(parts, nb);
    scanC_k<<<nb, 256, 0, stream>>>(deg, incl, parts, off, cur, dinv, n);
    fill_ranged_k<<<NRANGE * G, 256, 0, stream>>>(ei, cur, csr, E, n, G);
    gemm1_k<<<(n + 15) / 16, 256, 0, stream>>>(x, W1, h1, n);
    agg1_gather_k<<<(n + 3) / 4, 256, 0, stream>>>(off, deg, csr, dinv, h1, b1, z1, n);
    gemm2_k<<<(n * OUT_CH + 255) / 256, 256, 0, stream>>>(z1, W2, h2, n);
    agg2_final_k<<<(n + 31) / 32, 256, 0, stream>>>(off, deg, csr, dinv, h2, b2, out, n);
}

// Round 7
// 540.668 us; speedup vs baseline: 2.1472x; 1.0045x over previous
//
#include <hip/hip_runtime.h>
#include <hip/hip_fp16.h>

#define IN_CH  128
#define HID_CH 64
#define OUT_CH 8
#define NRANGE 8
#define CHUNK  4096
#define BUCKCAP 432768   // E/8 + 6-sigma headroom

// edge_index arrives as int32. src = ei[0..E), dst = ei[E..2E).

// ---------- 1. histogram of dst degrees ----------
__global__ void hist_k(const int* __restrict__ dst, int* __restrict__ deg, int E) {
    int e = blockIdx.x * blockDim.x + threadIdx.x;
    if (e < E) atomicAdd(&deg[dst[e]], 1);
}

// ---------- 2a. per-block inclusive scan ----------
__global__ __launch_bounds__(256) void scanA_k(const int* __restrict__ deg,
                                               int* __restrict__ incl,
                                               int* __restrict__ parts, int n) {
    __shared__ int sd[256];
    int t = threadIdx.x, v = blockIdx.x * 256 + t;
    int x = (v < n) ? deg[v] : 0;
    sd[t] = x; __syncthreads();
    for (int o = 1; o < 256; o <<= 1) {
        int y = (t >= o) ? sd[t - o] : 0;
        __syncthreads();
        sd[t] += y; __syncthreads();
    }
    if (v < n) incl[v] = sd[t];
    if (t == 255) parts[blockIdx.x] = sd[255];
}

// ---------- 2b. scan of block totals ----------
__global__ __launch_bounds__(512) void scanB_k(int* __restrict__ parts, int nb) {
    __shared__ int sd[512];
    int t = threadIdx.x;
    int x = (t < nb) ? parts[t] : 0;
    sd[t] = x; __syncthreads();
    for (int o = 1; o < 512; o <<= 1) {
        int y = (t >= o) ? sd[t - o] : 0;
        __syncthreads();
        sd[t] += y; __syncthreads();
    }
    parts[t] = sd[t] - x;   // exclusive
}

// ---------- 2c. finalize off/cur/dinv ----------
__global__ void scanC_k(const int* __restrict__ deg, const int* __restrict__ incl,
                        const int* __restrict__ parts, int* __restrict__ off,
                        int* __restrict__ cur, float* __restrict__ dinv, int n) {
    int v = blockIdx.x * blockDim.x + threadIdx.x;
    if (v >= n) return;
    int d = deg[v];
    int o = parts[blockIdx.x] + incl[v] - d;
    off[v] = o;
    cur[v] = o;
    dinv[v] = rsqrtf((float)d + 1.0f);   // +1 self-loop
}

// ---------- 3a. partition edges into NRANGE dst-range buckets ----------
// wave-ballot compaction; per-block LDS counters -> 8 global atomics/block
__global__ __launch_bounds__(256) void partA_k(const int* __restrict__ ei, int E, int RSZ,
                                               int* __restrict__ bcnt,
                                               int2* __restrict__ bucket) {
    __shared__ int cnt[NRANGE], base[NRANGE], curl[NRANGE];
    int tid = threadIdx.x, lane = tid & 63;
    unsigned long long lt = lane ? ((~0ull) >> (64 - lane)) : 0ull;
    if (tid < NRANGE) cnt[tid] = 0;
    __syncthreads();
    int e0 = blockIdx.x * CHUNK;
    // pass 1: count per range (ballot-aggregated)
    for (int i = tid; i < CHUNK; i += 256) {
        int e = e0 + i;
        int r = (e < E) ? ei[E + e] / RSZ : -1;
        for (int rr = 0; rr < NRANGE; ++rr) {
            unsigned long long m = __ballot(r == rr);
            if (m && lane == (__ffsll((unsigned long long)m) - 1))
                atomicAdd(&cnt[rr], (int)__popcll(m));
        }
    }
    __syncthreads();
    if (tid < NRANGE) { base[tid] = atomicAdd(&bcnt[tid * 16], cnt[tid]); curl[tid] = 0; }
    __syncthreads();
    // pass 2: dense bucket writes
    for (int i = tid; i < CHUNK; i += 256) {
        int e = e0 + i;
        int s = 0, d = 0, r = -1;
        if (e < E) { s = ei[e]; d = ei[E + e]; r = d / RSZ; }
        for (int rr = 0; rr < NRANGE; ++rr) {
            unsigned long long m = __ballot(r == rr);
            if (!m) continue;
            int leader = __ffsll((unsigned long long)m) - 1;
            int wb = 0;
            if (lane == leader) wb = atomicAdd(&curl[rr], (int)__popcll(m));
            wb = __shfl(wb, leader, 64);
            if (r == rr)
                bucket[(size_t)rr * BUCKCAP + base[rr] + wb + (int)__popcll(m & lt)] =
                    make_int2(s, d);
        }
    }
}

// ---------- 3b. scatter each bucket into its L2-local csr region ----------
__global__ __launch_bounds__(256) void partB_k(const int2* __restrict__ bucket,
                                               const int* __restrict__ bcnt,
                                               int* __restrict__ cur,
                                               int* __restrict__ csr, int G2) {
    int r = blockIdx.x & (NRANGE - 1);
    int j = blockIdx.x >> 3;
    int cnt = bcnt[r * 16];
    const int2* b = bucket + (size_t)r * BUCKCAP;
    for (int i0 = j * 256; i0 < cnt; i0 += G2 * 256) {
        int i = i0 + threadIdx.x;
        if (i < cnt) {
            int2 p = b[i];
            int slot = atomicAdd(&cur[p.y], 1);
            csr[slot] = p.x;
        }
    }
}

// ---------- 4. h1' = dinv * (x @ W1) -> fp16 ----------
__global__ __launch_bounds__(256) void gemm1_k(const float* __restrict__ x,
                                               const float* __restrict__ W,
                                               const float* __restrict__ dinv,
                                               __half* __restrict__ h, int n) {
    __shared__ float Ws[IN_CH * HID_CH];     // 32 KB
    __shared__ float xs[16][IN_CH];          // 8 KB
    int tid = threadIdx.x;
    for (int i = tid; i < IN_CH * HID_CH; i += 256) Ws[i] = W[i];
    int node0 = blockIdx.x * 16;
    for (int i = tid; i < 16 * IN_CH; i += 256) {
        int nn = i >> 7, k = i & 127;
        int node = node0 + nn;
        xs[nn][k] = (node < n) ? x[(size_t)node * IN_CH + k] : 0.0f;
    }
    __syncthreads();
    int nl = tid >> 6, oc = tid & 63;
    float a0 = 0, a1 = 0, a2 = 0, a3 = 0;
#pragma unroll 8
    for (int k = 0; k < IN_CH; ++k) {
        float w = Ws[k * HID_CH + oc];
        a0 += xs[nl][k] * w;
        a1 += xs[nl + 4][k] * w;
        a2 += xs[nl + 8][k] * w;
        a3 += xs[nl + 12][k] * w;
    }
    int v0 = node0 + nl;
    if (v0      < n) h[(size_t)(v0     ) * HID_CH + oc] = __float2half(a0 * dinv[v0]);
    if (v0 + 4  < n) h[(size_t)(v0 + 4 ) * HID_CH + oc] = __float2half(a1 * dinv[v0 + 4]);
    if (v0 + 8  < n) h[(size_t)(v0 + 8 ) * HID_CH + oc] = __float2half(a2 * dinv[v0 + 8]);
    if (v0 + 12 < n) h[(size_t)(v0 + 12) * HID_CH + oc] = __float2half(a3 * dinv[v0 + 12]);
}

// ---------- 5. layer-1 gather (pre-scaled rows, 4-way MLP) + bias + relu -> fp16 ----------
__global__ __launch_bounds__(256) void agg1_gather_k(const int* __restrict__ off,
                                                     const int* __restrict__ deg,
                                                     const int* __restrict__ csr,
                                                     const float* __restrict__ dinv,
                                                     const __half* __restrict__ h,
                                                     const float* __restrict__ b,
                                                     __half* __restrict__ z, int n) {
    int node = blockIdx.x * 4 + (threadIdx.x >> 6);
    int lane = threadIdx.x & 63;
    if (node >= n) return;
    float dv = dinv[node];
    int o = off[node], dg = deg[node];
    float a0 = 0, a1 = 0, a2 = 0, a3 = 0;
    int i = o, end = o + dg;
    for (; i + 3 < end; i += 4) {
        int s0 = csr[i], s1 = csr[i + 1], s2 = csr[i + 2], s3 = csr[i + 3];
        a0 += __half2float(h[(size_t)s0 * HID_CH + lane]);
        a1 += __half2float(h[(size_t)s1 * HID_CH + lane]);
        a2 += __half2float(h[(size_t)s2 * HID_CH + lane]);
        a3 += __half2float(h[(size_t)s3 * HID_CH + lane]);
    }
    for (; i < end; ++i)
        a0 += __half2float(h[(size_t)csr[i] * HID_CH + lane]);
    float self = __half2float(h[(size_t)node * HID_CH + lane]);
    float val = dv * ((a0 + a1) + (a2 + a3) + self) + b[lane];
    z[(size_t)node * HID_CH + lane] = __float2half(fmaxf(val, 0.0f));
}

// ---------- 6. h2' = dinv * (z @ W2) -> fp16 (1 node/thread, 8 accs) ----------
__global__ __launch_bounds__(256) void gemm2_k(const __half* __restrict__ z,
                                               const float* __restrict__ W,
                                               const float* __restrict__ dinv,
                                               __half* __restrict__ h2, int n) {
    __shared__ float Ws[HID_CH * OUT_CH];
    int tid = threadIdx.x;
    for (int i = tid; i < HID_CH * OUT_CH; i += 256) Ws[i] = W[i];
    __syncthreads();
    int node = blockIdx.x * 256 + tid;
    if (node >= n) return;
    float acc[OUT_CH];
#pragma unroll
    for (int c = 0; c < OUT_CH; ++c) acc[c] = 0.0f;
    const __half2* zr = (const __half2*)(z + (size_t)node * HID_CH);
#pragma unroll 8
    for (int k2 = 0; k2 < HID_CH / 2; ++k2) {
        float2 v = __half22float2(zr[k2]);
        int k = k2 * 2;
#pragma unroll
        for (int c = 0; c < OUT_CH; ++c)
            acc[c] += v.x * Ws[k * OUT_CH + c] + v.y * Ws[(k + 1) * OUT_CH + c];
    }
    float dv = dinv[node];
    __half2* o2 = (__half2*)(h2 + (size_t)node * OUT_CH);
#pragma unroll
    for (int c2 = 0; c2 < OUT_CH / 2; ++c2)
        o2[c2] = __floats2half2_rn(dv * acc[2 * c2], dv * acc[2 * c2 + 1]);
}

// ---------- 7. layer-2 gather (pre-scaled) + bias + log_softmax ----------
__global__ __launch_bounds__(256) void agg2_final_k(const int* __restrict__ off,
                                                    const int* __restrict__ deg,
                                                    const int* __restrict__ csr,
                                                    const float* __restrict__ dinv,
                                                    const __half* __restrict__ h2,
                                                    const float* __restrict__ b,
                                                    float* __restrict__ out, int n) {
    int tid = threadIdx.x;
    int node = blockIdx.x * 32 + (tid >> 3);
    int c = tid & 7;
    if (node >= n) return;
    float dv = dinv[node];
    int o = off[node], dg = deg[node];
    float a0 = 0, a1 = 0;
    int i = o, end = o + dg;
    for (; i + 1 < end; i += 2) {
        int s0 = csr[i], s1 = csr[i + 1];
        a0 += __half2float(h2[(size_t)s0 * OUT_CH + c]);
        a1 += __half2float(h2[(size_t)s1 * OUT_CH + c]);
    }
    if (i < end) a0 += __half2float(h2[(size_t)csr[i] * OUT_CH + c]);
    float self = __half2float(h2[(size_t)node * OUT_CH + c]);
    float val = dv * (a0 + a1 + self) + b[c];
    float m = val;
    m = fmaxf(m, __shfl_xor(m, 1, 8));
    m = fmaxf(m, __shfl_xor(m, 2, 8));
    m = fmaxf(m, __shfl_xor(m, 4, 8));
    float s8 = expf(val - m);
    s8 += __shfl_xor(s8, 1, 8);
    s8 += __shfl_xor(s8, 2, 8);
    s8 += __shfl_xor(s8, 4, 8);
    out[(size_t)node * OUT_CH + c] = val - m - logf(s8);
}

extern "C" void kernel_launch(void* const* d_in, const int* in_sizes, int n_in,
                              void* d_out, int out_size, void* d_ws, size_t ws_size,
                              hipStream_t stream) {
    const float* x  = (const float*)d_in[0];
    const int*   ei = (const int*)d_in[1];
    const float* W1 = (const float*)d_in[2];
    const float* b1 = (const float*)d_in[3];
    const float* W2 = (const float*)d_in[4];
    const float* b2 = (const float*)d_in[5];
    float* out = (float*)d_out;

    const int n = in_sizes[0] / IN_CH;      // 100000
    const int E = in_sizes[1] / 2;          // 3200000
    const int NP = 100352;
    const int RSZ = (n + NRANGE - 1) / NRANGE;

    // ---- workspace layout (~42.5 MB) ----
    int*    deg  = (int*)d_ws;                       // [NP]
    int*    incl = deg  + NP;                        // [NP]
    int*    parts= incl + NP;                        // [512]
    int*    off  = parts+ 512;                       // [NP]
    int*    cur  = off  + NP;                        // [NP]
    float*  dinv = (float*)(cur + NP);               // [NP]
    int*    bcnt = (int*)(dinv + NP);                // [128] (8 counters, padded)
    int*    csr  = bcnt + 128;                       // [E]
    // region after csr: buckets (27.7MB) during fill, then h1'+z1 (25.6MB)
    int2*   bucket = (int2*)(csr + E);
    __half* h1   = (__half*)(csr + E);               // [NP*64] fp16, pre-scaled
    __half* z1   = h1 + (size_t)NP * HID_CH;         // [NP*64] fp16
    __half* h2   = h1;                               // overlay (h1 dead after agg1)

    const int nb = (n + 255) / 256;
    const int G2 = 128;

    hipMemsetAsync(deg, 0, (size_t)n * sizeof(int), stream);
    hipMemsetAsync(bcnt, 0, 128 * sizeof(int), stream);
    hist_k <<<(E + 255) / 256, 256, 0, stream>>>(ei + E, deg, E);
    scanA_k<<<nb, 256, 0, stream>>>(deg, incl, parts, n);
    scanB_k<<<1, 512, 0, stream>>>(parts, nb);
    scanC_k<<<nb, 256, 0, stream>>>(deg, incl, parts, off, cur, dinv, n);
    partA_k<<<(E + CHUNK - 1) / CHUNK, 256, 0, stream>>>(ei, E, RSZ, bcnt, bucket);
    partB_k<<<NRANGE * G2, 256, 0, stream>>>(bucket, bcnt, cur, csr, G2);
    gemm1_k<<<(n + 15) / 16, 256, 0, stream>>>(x, W1, dinv, h1, n);
    agg1_gather_k<<<(n + 3) / 4, 256, 0, stream>>>(off, deg, csr, dinv, h1, b1, z1, n);
    gemm2_k<<<(n + 255) / 256, 256, 0, stream>>>(z1, W2, dinv, h2, n);
    agg2_final_k<<<(n + 31) / 32, 256, 0, stream>>>(off, deg, csr, dinv, h2, b2, out, n);
}

// Round 8
// 519.448 us; speedup vs baseline: 2.2349x; 1.0409x over previous
//
#include <hip/hip_runtime.h>
#include <hip/hip_fp16.h>

#define IN_CH  128
#define HID_CH 64
#define OUT_CH 8
#define NRANGE 8
#define CHUNK  4096
#define BUCKCAP 432768   // E/8 + huge headroom

typedef unsigned long long ull;

// edge_index arrives as int32. src = ei[0..E), dst = ei[E..2E).

// ---------- 1. histogram of dst degrees ----------
__global__ void hist_k(const int* __restrict__ dst, int* __restrict__ deg, int E) {
    int e = blockIdx.x * blockDim.x + threadIdx.x;
    if (e < E) atomicAdd(&deg[dst[e]], 1);
}

// ---------- 2a. per-block inclusive scan ----------
__global__ __launch_bounds__(256) void scanA_k(const int* __restrict__ deg,
                                               int* __restrict__ incl,
                                               int* __restrict__ parts, int n) {
    __shared__ int sd[256];
    int t = threadIdx.x, v = blockIdx.x * 256 + t;
    int x = (v < n) ? deg[v] : 0;
    sd[t] = x; __syncthreads();
    for (int o = 1; o < 256; o <<= 1) {
        int y = (t >= o) ? sd[t - o] : 0;
        __syncthreads();
        sd[t] += y; __syncthreads();
    }
    if (v < n) incl[v] = sd[t];
    if (t == 255) parts[blockIdx.x] = sd[255];
}

// ---------- 2b. scan of block totals ----------
__global__ __launch_bounds__(512) void scanB_k(int* __restrict__ parts, int nb) {
    __shared__ int sd[512];
    int t = threadIdx.x;
    int x = (t < nb) ? parts[t] : 0;
    sd[t] = x; __syncthreads();
    for (int o = 1; o < 512; o <<= 1) {
        int y = (t >= o) ? sd[t - o] : 0;
        __syncthreads();
        sd[t] += y; __syncthreads();
    }
    parts[t] = sd[t] - x;   // exclusive
}

// ---------- 2c. finalize off/cur/dinv ----------
__global__ void scanC_k(const int* __restrict__ deg, const int* __restrict__ incl,
                        const int* __restrict__ parts, int* __restrict__ off,
                        int* __restrict__ cur, float* __restrict__ dinv, int n) {
    int v = blockIdx.x * blockDim.x + threadIdx.x;
    if (v >= n) return;
    int d = deg[v];
    int o = parts[blockIdx.x] + incl[v] - d;
    off[v] = o;
    cur[v] = o;
    dinv[v] = rsqrtf((float)d + 1.0f);   // +1 self-loop
}

// ---------- 3a. partition edges into NRANGE dst-range buckets (NT stores) ----------
__global__ __launch_bounds__(256) void partA_k(const int* __restrict__ ei, int E, int RSZ,
                                               int* __restrict__ bcnt,
                                               ull* __restrict__ bucket) {
    __shared__ int cnt[NRANGE], base[NRANGE], curl[NRANGE];
    int tid = threadIdx.x, lane = tid & 63;
    unsigned long long lt = lane ? ((~0ull) >> (64 - lane)) : 0ull;
    if (tid < NRANGE) cnt[tid] = 0;
    __syncthreads();
    int e0 = blockIdx.x * CHUNK;
    for (int i = tid; i < CHUNK; i += 256) {
        int e = e0 + i;
        int r = (e < E) ? ei[E + e] / RSZ : -1;
        for (int rr = 0; rr < NRANGE; ++rr) {
            unsigned long long m = __ballot(r == rr);
            if (m && lane == (__ffsll((unsigned long long)m) - 1))
                atomicAdd(&cnt[rr], (int)__popcll(m));
        }
    }
    __syncthreads();
    if (tid < NRANGE) { base[tid] = atomicAdd(&bcnt[tid * 16], cnt[tid]); curl[tid] = 0; }
    __syncthreads();
    for (int i = tid; i < CHUNK; i += 256) {
        int e = e0 + i;
        int s = 0, d = 0, r = -1;
        if (e < E) { s = ei[e]; d = ei[E + e]; r = d / RSZ; }
        for (int rr = 0; rr < NRANGE; ++rr) {
            unsigned long long m = __ballot(r == rr);
            if (!m) continue;
            int leader = __ffsll((unsigned long long)m) - 1;
            int wb = 0;
            if (lane == leader) wb = atomicAdd(&curl[rr], (int)__popcll(m));
            wb = __shfl(wb, leader, 64);
            if (r == rr) {
                ull v = (ull)(unsigned)s | ((ull)(unsigned)d << 32);
                __builtin_nontemporal_store(v,
                    &bucket[(size_t)rr * BUCKCAP + base[rr] + wb + (int)__popcll(m & lt)]);
            }
        }
    }
}

// ---------- 3b. scatter each bucket into its L2-local csr region (NT loads) ----------
__global__ __launch_bounds__(256) void partB_k(const ull* __restrict__ bucket,
                                               const int* __restrict__ bcnt,
                                               int* __restrict__ cur,
                                               int* __restrict__ csr, int G2) {
    int r = blockIdx.x & (NRANGE - 1);
    int j = blockIdx.x >> 3;
    int cnt = bcnt[r * 16];
    const ull* b = bucket + (size_t)r * BUCKCAP;
    for (int i0 = j * 256; i0 < cnt; i0 += G2 * 256) {
        int i = i0 + threadIdx.x;
        if (i < cnt) {
            ull v = __builtin_nontemporal_load(&b[i]);   // zero-reuse stream: keep out of L2
            int s = (int)(v & 0xffffffffu), d = (int)(v >> 32);
            int slot = atomicAdd(&cur[d], 1);
            csr[slot] = s;
        }
    }
}

// ---------- 4. h1' = dinv * (x @ W1) -> fp16 ----------
__global__ __launch_bounds__(256) void gemm1_k(const float* __restrict__ x,
                                               const float* __restrict__ W,
                                               const float* __restrict__ dinv,
                                               __half* __restrict__ h, int n) {
    __shared__ float Ws[IN_CH * HID_CH];     // 32 KB
    __shared__ float xs[16][IN_CH];          // 8 KB
    int tid = threadIdx.x;
    for (int i = tid; i < IN_CH * HID_CH; i += 256) Ws[i] = W[i];
    int node0 = blockIdx.x * 16;
    for (int i = tid; i < 16 * IN_CH; i += 256) {
        int nn = i >> 7, k = i & 127;
        int node = node0 + nn;
        xs[nn][k] = (node < n) ? x[(size_t)node * IN_CH + k] : 0.0f;
    }
    __syncthreads();
    int nl = tid >> 6, oc = tid & 63;
    float a0 = 0, a1 = 0, a2 = 0, a3 = 0;
#pragma unroll 8
    for (int k = 0; k < IN_CH; ++k) {
        float w = Ws[k * HID_CH + oc];
        a0 += xs[nl][k] * w;
        a1 += xs[nl + 4][k] * w;
        a2 += xs[nl + 8][k] * w;
        a3 += xs[nl + 12][k] * w;
    }
    int v0 = node0 + nl;
    if (v0      < n) h[(size_t)(v0     ) * HID_CH + oc] = __float2half(a0 * dinv[v0]);
    if (v0 + 4  < n) h[(size_t)(v0 + 4 ) * HID_CH + oc] = __float2half(a1 * dinv[v0 + 4]);
    if (v0 + 8  < n) h[(size_t)(v0 + 8 ) * HID_CH + oc] = __float2half(a2 * dinv[v0 + 8]);
    if (v0 + 12 < n) h[(size_t)(v0 + 12) * HID_CH + oc] = __float2half(a3 * dinv[v0 + 12]);
}

// ---------- 5. layer-1 gather (pre-scaled rows, 8-way MLP) + bias + relu -> fp16 ----------
__global__ __launch_bounds__(256) void agg1_gather_k(const int* __restrict__ off,
                                                     const int* __restrict__ deg,
                                                     const int* __restrict__ csr,
                                                     const float* __restrict__ dinv,
                                                     const __half* __restrict__ h,
                                                     const float* __restrict__ b,
                                                     __half* __restrict__ z, int n) {
    int node = blockIdx.x * 4 + (threadIdx.x >> 6);
    int lane = threadIdx.x & 63;
    if (node >= n) return;
    float dv = dinv[node];
    int o = off[node], dg = deg[node];
    float a0 = 0, a1 = 0, a2 = 0, a3 = 0, a4 = 0, a5 = 0, a6 = 0, a7 = 0;
    int i = o, end = o + dg;
    for (; i + 7 < end; i += 8) {
        int s0 = csr[i], s1 = csr[i + 1], s2 = csr[i + 2], s3 = csr[i + 3];
        int s4 = csr[i + 4], s5 = csr[i + 5], s6 = csr[i + 6], s7 = csr[i + 7];
        a0 += __half2float(h[(size_t)s0 * HID_CH + lane]);
        a1 += __half2float(h[(size_t)s1 * HID_CH + lane]);
        a2 += __half2float(h[(size_t)s2 * HID_CH + lane]);
        a3 += __half2float(h[(size_t)s3 * HID_CH + lane]);
        a4 += __half2float(h[(size_t)s4 * HID_CH + lane]);
        a5 += __half2float(h[(size_t)s5 * HID_CH + lane]);
        a6 += __half2float(h[(size_t)s6 * HID_CH + lane]);
        a7 += __half2float(h[(size_t)s7 * HID_CH + lane]);
    }
    for (; i < end; ++i)
        a0 += __half2float(h[(size_t)csr[i] * HID_CH + lane]);
    float self = __half2float(h[(size_t)node * HID_CH + lane]);
    float val = dv * (((a0 + a1) + (a2 + a3)) + ((a4 + a5) + (a6 + a7)) + self) + b[lane];
    z[(size_t)node * HID_CH + lane] = __float2half(fmaxf(val, 0.0f));
}

// ---------- 6. h2' = dinv * (z @ W2) -> fp16 ----------
__global__ __launch_bounds__(256) void gemm2_k(const __half* __restrict__ z,
                                               const float* __restrict__ W,
                                               const float* __restrict__ dinv,
                                               __half* __restrict__ h2, int n) {
    __shared__ float Ws[HID_CH * OUT_CH];
    int tid = threadIdx.x;
    for (int i = tid; i < HID_CH * OUT_CH; i += 256) Ws[i] = W[i];
    __syncthreads();
    int node = blockIdx.x * 256 + tid;
    if (node >= n) return;
    float acc[OUT_CH];
#pragma unroll
    for (int c = 0; c < OUT_CH; ++c) acc[c] = 0.0f;
    const __half2* zr = (const __half2*)(z + (size_t)node * HID_CH);
#pragma unroll 8
    for (int k2 = 0; k2 < HID_CH / 2; ++k2) {
        float2 v = __half22float2(zr[k2]);
        int k = k2 * 2;
#pragma unroll
        for (int c = 0; c < OUT_CH; ++c)
            acc[c] += v.x * Ws[k * OUT_CH + c] + v.y * Ws[(k + 1) * OUT_CH + c];
    }
    float dv = dinv[node];
    __half2* o2 = (__half2*)(h2 + (size_t)node * OUT_CH);
#pragma unroll
    for (int c2 = 0; c2 < OUT_CH / 2; ++c2)
        o2[c2] = __floats2half2_rn(dv * acc[2 * c2], dv * acc[2 * c2 + 1]);
}

// ---------- 7. layer-2 gather (pre-scaled, 4-way) + bias + log_softmax ----------
__global__ __launch_bounds__(256) void agg2_final_k(const int* __restrict__ off,
                                                    const int* __restrict__ deg,
                                                    const int* __restrict__ csr,
                                                    const float* __restrict__ dinv,
                                                    const __half* __restrict__ h2,
                                                    const float* __restrict__ b,
                                                    float* __restrict__ out, int n) {
    int tid = threadIdx.x;
    int node = blockIdx.x * 32 + (tid >> 3);
    int c = tid & 7;
    if (node >= n) return;
    float dv = dinv[node];
    int o = off[node], dg = deg[node];
    float a0 = 0, a1 = 0, a2 = 0, a3 = 0;
    int i = o, end = o + dg;
    for (; i + 3 < end; i += 4) {
        int s0 = csr[i], s1 = csr[i + 1], s2 = csr[i + 2], s3 = csr[i + 3];
        a0 += __half2float(h2[(size_t)s0 * OUT_CH + c]);
        a1 += __half2float(h2[(size_t)s1 * OUT_CH + c]);
        a2 += __half2float(h2[(size_t)s2 * OUT_CH + c]);
        a3 += __half2float(h2[(size_t)s3 * OUT_CH + c]);
    }
    for (; i < end; ++i) a0 += __half2float(h2[(size_t)csr[i] * OUT_CH + c]);
    float self = __half2float(h2[(size_t)node * OUT_CH + c]);
    float val = dv * ((a0 + a1) + (a2 + a3) + self) + b[c];
    float m = val;
    m = fmaxf(m, __shfl_xor(m, 1, 8));
    m = fmaxf(m, __shfl_xor(m, 2, 8));
    m = fmaxf(m, __shfl_xor(m, 4, 8));
    float s8 = expf(val - m);
    s8 += __shfl_xor(s8, 1, 8);
    s8 += __shfl_xor(s8, 2, 8);
    s8 += __shfl_xor(s8, 4, 8);
    out[(size_t)node * OUT_CH + c] = val - m - logf(s8);
}

extern "C" void kernel_launch(void* const* d_in, const int* in_sizes, int n_in,
                              void* d_out, int out_size, void* d_ws, size_t ws_size,
                              hipStream_t stream) {
    const float* x  = (const float*)d_in[0];
    const int*   ei = (const int*)d_in[1];
    const float* W1 = (const float*)d_in[2];
    const float* b1 = (const float*)d_in[3];
    const float* W2 = (const float*)d_in[4];
    const float* b2 = (const float*)d_in[5];
    float* out = (float*)d_out;

    const int n = in_sizes[0] / IN_CH;      // 100000
    const int E = in_sizes[1] / 2;          // 3200000
    const int NP = 100352;
    const int RSZ = (n + NRANGE - 1) / NRANGE;

    // ---- workspace layout ----
    int*    deg  = (int*)d_ws;                       // [NP]
    int*    incl = deg  + NP;                        // [NP]
    int*    parts= incl + NP;                        // [512]
    int*    off  = parts+ 512;                       // [NP]
    int*    cur  = off  + NP;                        // [NP]
    float*  dinv = (float*)(cur + NP);               // [NP]
    int*    bcnt = (int*)(dinv + NP);                // [128]
    int*    csr  = bcnt + 128;                       // [E]
    ull*    bucket = (ull*)(csr + E);                // [8*BUCKCAP] during fill
    __half* h1   = (__half*)(csr + E);               // overlay after partB
    __half* z1   = h1 + (size_t)NP * HID_CH;         // [NP*64] fp16
    __half* h2   = h1;                               // overlay (h1 dead after agg1)

    const int nb = (n + 255) / 256;
    const int G2 = 256;

    hipMemsetAsync(deg, 0, (size_t)n * sizeof(int), stream);
    hipMemsetAsync(bcnt, 0, 128 * sizeof(int), stream);
    hist_k <<<(E + 255) / 256, 256, 0, stream>>>(ei + E, deg, E);
    scanA_k<<<nb, 256, 0, stream>>>(deg, incl, parts, n);
    scanB_k<<<1, 512, 0, stream>>>(parts, nb);
    scanC_k<<<nb, 256, 0, stream>>>(deg, incl, parts, off, cur, dinv, n);
    partA_k<<<(E + CHUNK - 1) / CHUNK, 256, 0, stream>>>(ei, E, RSZ, bcnt, bucket);
    partB_k<<<NRANGE * G2, 256, 0, stream>>>(bucket, bcnt, cur, csr, G2);
    gemm1_k<<<(n + 15) / 16, 256, 0, stream>>>(x, W1, dinv, h1, n);
    agg1_gather_k<<<(n + 3) / 4, 256, 0, stream>>>(off, deg, csr, dinv, h1, b1, z1, n);
    gemm2_k<<<(n + 255) / 256, 256, 0, stream>>>(z1, W2, dinv, h2, n);
    agg2_final_k<<<(n + 31) / 32, 256, 0, stream>>>(off, deg, csr, dinv, h2, b2, out, n);
}